// Round 10
// baseline (909.704 us; speedup 1.0000x reference)
//
#include <hip/hip_runtime.h>

// OnsetLSTM: 2-layer LSTM, B=256, T=512, D=160, H=128, fp32 in/out.
//
// Architecture (R8/R9): x-side gate pre-acts via MFMA GEMM; recurrence keeps
// only W_hh in regs (64 f16 pairs/thread at 512thr, under hipcc's
// 65536-VGPR/workgroup cap). Chunked layer pipeline NC=4: L0 chunk c runs
// concurrently with L1 chunk c-1 (2 blocks/CU). Gx stored t-transposed so the
// rec loads 8 steps/gate with one dwordx4 (vmcnt drain amortized 1/8 barriers).
//
// R9->R10: ONE change. R9's rec measured ~520 wave-VALU instrs/step vs ~170
// modeled -> the __has_builtin(fdot2) fallback (cvt+fma per element, ~6 ops/
// pair) was almost certainly compiled in. Pin the real CDNA4 VOP3P dot:
// inline asm v_dot2_f32_f16 (1 op/pair).

typedef _Float16 f16;
typedef _Float16 f16x8 __attribute__((ext_vector_type(8)));
typedef float f32x4 __attribute__((ext_vector_type(4)));

#define B_  256
#define T_  512
#define HID 128
#define NG  512
#define KX0 160
#define NC  4
#define TC  128   // T_/NC

static __device__ __forceinline__ unsigned pack2(float a, float b) {
  union { f16 h[2]; unsigned u; } v;
  v.h[0] = (f16)a; v.h[1] = (f16)b;
  return v.u;
}

// v_dot2_f32_f16: d = a.h0*b.h0 + a.h1*b.h1 + c  (CDNA4 VOP3P, single instr)
static __device__ __forceinline__ float dot2f(unsigned a, unsigned b, float c) {
  float d;
  asm("v_dot2_f32_f16 %0, %1, %2, %3" : "=v"(d) : "v"(a), "v"(b), "v"(c));
  return d;
}

static __device__ __forceinline__ float fast_rcp(float x) {
#if __has_builtin(__builtin_amdgcn_rcpf)
  return __builtin_amdgcn_rcpf(x);
#else
  return 1.0f / x;
#endif
}
static __device__ __forceinline__ float fast_exp2(float x) {
#if __has_builtin(__builtin_amdgcn_exp2f)
  return __builtin_amdgcn_exp2f(x);
#else
  return exp2f(x);
#endif
}
static __device__ __forceinline__ float sigm(float x) {
  return fast_rcp(1.0f + fast_exp2(x * -1.44269504f));
}
static __device__ __forceinline__ float tanh_f(float x) {
  float e = fast_exp2(x * 2.885390082f);
  return 1.0f - 2.0f * fast_rcp(e + 1.0f);
}

template <int CTRL>
static __device__ __forceinline__ float qp_add(float v) {
  int iv = __builtin_bit_cast(int, v);
  int t = __builtin_amdgcn_update_dpp(iv, iv, CTRL, 0xF, 0xF, true);
  return v + __builtin_bit_cast(float, t);
}

// extract f16 #j (compile-time after unroll) from an 8-half batch
static __device__ __forceinline__ float gxval(const uint4& g, int j) {
  unsigned w = (j >> 1) == 0 ? g.x : (j >> 1) == 1 ? g.y : (j >> 1) == 2 ? g.z : g.w;
  unsigned hs = (j & 1) ? (w >> 16) : (w & 0xffffu);
  f16 v = __builtin_bit_cast(f16, (unsigned short)hs);
  return (float)v;
}

// ======================= GEMM: Gx = A @ W^T, transposed-t store =============
// A: [B][Tc][K] (f32 strided x, or f16 contiguous h1). W: [512][K] f32.
// D layout: [(b*128 + cell)*4 + gate][t], t in [0,TC).
template <int K, bool AF16>
__global__ __launch_bounds__(256) void gemm_xw(
    const void* __restrict__ Aptr, size_t bStride,
    const float* __restrict__ W, f16* __restrict__ D) {
  constexpr int KP = K + 8;
  __shared__ f16 As[128][KP];
  __shared__ f16 Bs[64][KP];
  const int tid = threadIdx.x;
  const int mtile = blockIdx.x, ntile = blockIdx.y;

  if (AF16) {
    const f16* A = (const f16*)Aptr;
    for (int i = tid; i < 128 * (K / 8); i += 256) {
      int r = i / (K / 8), kk = (i % (K / 8)) * 8;
      size_t grow = (size_t)mtile * 128 + r;
      uint4 v = *(const uint4*)(A + grow * K + kk);
      *(uint4*)&As[r][kk] = v;
    }
  } else {
    const float* A = (const float*)Aptr;
    for (int i = tid; i < 128 * (K / 4); i += 256) {
      int r = i / (K / 4), kk = (i % (K / 4)) * 4;
      int grow = mtile * 128 + r;
      int bb = grow >> 7, tt = grow & (TC - 1);
      const float* p = A + (size_t)bb * bStride + (size_t)tt * K + kk;
      float4 v = *(const float4*)p;
      uint2 u;
      u.x = pack2(v.x, v.y);
      u.y = pack2(v.z, v.w);
      *(uint2*)&As[r][kk] = u;
    }
  }
  for (int i = tid; i < 64 * (K / 4); i += 256) {
    int r = i / (K / 4), kk = (i % (K / 4)) * 4;
    const float* p = W + (size_t)(ntile * 64 + r) * K + kk;
    float4 v = *(const float4*)p;
    uint2 u;
    u.x = pack2(v.x, v.y);
    u.y = pack2(v.z, v.w);
    *(uint2*)&Bs[r][kk] = u;
  }
  __syncthreads();

  const int w = tid >> 6, l = tid & 63;
  const int lr = l & 15, lg = l >> 4;
  f32x4 acc[2][4] = {};
#pragma unroll
  for (int ks = 0; ks < K / 32; ++ks) {
    f16x8 a0 = *(const f16x8*)&As[w * 32 + lr][ks * 32 + lg * 8];
    f16x8 a1 = *(const f16x8*)&As[w * 32 + 16 + lr][ks * 32 + lg * 8];
    f16x8 bf[4];
#pragma unroll
    for (int nj = 0; nj < 4; ++nj)
      bf[nj] = *(const f16x8*)&Bs[nj * 16 + lr][ks * 32 + lg * 8];
#pragma unroll
    for (int nj = 0; nj < 4; ++nj) {
      acc[0][nj] = __builtin_amdgcn_mfma_f32_16x16x32_f16(a0, bf[nj], acc[0][nj], 0, 0, 0);
      acc[1][nj] = __builtin_amdgcn_mfma_f32_16x16x32_f16(a1, bf[nj], acc[1][nj], 0, 0, 0);
    }
  }
  // C/D layout (m89): col = lane&15, row = (lane>>4)*4 + q. Rows are t -> the
  // 4 q's are 4 consecutive t of the same (b, col): one 8B store.
#pragma unroll
  for (int mi = 0; mi < 2; ++mi) {
#pragma unroll
    for (int nj = 0; nj < 4; ++nj) {
      int col = ntile * 64 + nj * 16 + lr;
      int cell = col & 127, gate = col >> 7;
      int rowbase = mtile * 128 + w * 32 + mi * 16 + lg * 4;
      int bb = rowbase >> 7, tt = rowbase & (TC - 1);
      unsigned lo = pack2(acc[mi][nj][0], acc[mi][nj][1]);
      unsigned hi = pack2(acc[mi][nj][2], acc[mi][nj][3]);
      size_t idx = (((size_t)bb * HID + cell) * 4 + gate) * TC + tt;
      uint2 u; u.x = lo; u.y = hi;
      *(uint2*)(D + idx) = u;
    }
  }
}

// ======================= Recurrence (chunk, possibly 2 layers) ==============
struct RecArgs {
  const f16* Gx;      // [(b*128+cell)*4+gate][TC]
  const float* Whh;   // [512][128]
  const float* bih; const float* bhh;
  const float* hin; const float* cin;   // [B][128] f32
  float* hst; float* cst;               // [B][128] f32
  f16* h1out;                            // [B][TC][128] or null
  float* fin;                            // [B][128] or null
};

__global__ __launch_bounds__(512) void lstm_rec2(RecArgs A, RecArgs B, int nA) {
  const RecArgs& P = ((int)blockIdx.x < nA) ? A : B;
  const int b = ((int)blockIdx.x < nA) ? blockIdx.x : blockIdx.x - nA;
  const int tid = threadIdx.x;
  const int c = tid >> 2, s = tid & 3;
  __shared__ unsigned hbuf[2][64];

  unsigned wh[4][16];
  float bias[4];
#pragma unroll
  for (int g = 0; g < 4; ++g) {
    const int r = g * HID + c;
#pragma unroll
    for (int j = 0; j < 16; ++j) {
      int p = 16 * s + j;
      wh[g][j] = pack2(P.Whh[(size_t)r * HID + 2 * p], P.Whh[(size_t)r * HID + 2 * p + 1]);
    }
    bias[g] = P.bih[r] + P.bhh[r];
  }
  float cstate = P.cin[b * HID + c];
  if (tid < 64)
    hbuf[0][tid] = pack2(P.hin[b * HID + 2 * tid], P.hin[b * HID + 2 * tid + 1]);

  const f16* gxb = P.Gx + ((size_t)b * HID + c) * 4 * TC;
  f16* h1x = P.h1out ? P.h1out + (size_t)b * TC * HID + c : (f16*)nullptr;

  uint4 gA[4], gB[4];
#pragma unroll
  for (int g = 0; g < 4; ++g) gA[g] = *(const uint4*)(gxb + (size_t)g * TC + 0);
  __syncthreads();

  float hprev = 0.f;

  auto STEP = [&](const uint4 (&gx)[4], int t, int j) {
    // early store of previous step's h1 (ack retires before this step's barrier)
    if (h1x && s == 0 && t > 0) h1x[(size_t)(t - 1) * HID] = (f16)hprev;
    const uint4* hs4 = (const uint4*)&hbuf[t & 1][16 * s];
    float ai = 0.f, af = 0.f, ag = 0.f, ao = 0.f;
#pragma unroll
    for (int k = 0; k < 4; ++k) {
      uint4 v = hs4[k];
      ai = dot2f(v.x, wh[0][4 * k + 0], ai); ai = dot2f(v.y, wh[0][4 * k + 1], ai);
      ai = dot2f(v.z, wh[0][4 * k + 2], ai); ai = dot2f(v.w, wh[0][4 * k + 3], ai);
      af = dot2f(v.x, wh[1][4 * k + 0], af); af = dot2f(v.y, wh[1][4 * k + 1], af);
      af = dot2f(v.z, wh[1][4 * k + 2], af); af = dot2f(v.w, wh[1][4 * k + 3], af);
      ag = dot2f(v.x, wh[2][4 * k + 0], ag); ag = dot2f(v.y, wh[2][4 * k + 1], ag);
      ag = dot2f(v.z, wh[2][4 * k + 2], ag); ag = dot2f(v.w, wh[2][4 * k + 3], ag);
      ao = dot2f(v.x, wh[3][4 * k + 0], ao); ao = dot2f(v.y, wh[3][4 * k + 1], ao);
      ao = dot2f(v.z, wh[3][4 * k + 2], ao); ao = dot2f(v.w, wh[3][4 * k + 3], ao);
    }
    ai = qp_add<0xB1>(ai); ai = qp_add<0x4E>(ai);
    af = qp_add<0xB1>(af); af = qp_add<0x4E>(af);
    ag = qp_add<0xB1>(ag); ag = qp_add<0x4E>(ag);
    ao = qp_add<0xB1>(ao); ao = qp_add<0x4E>(ao);

    float iv = sigm(ai + bias[0] + gxval(gx[0], j));
    float fv = sigm(af + bias[1] + gxval(gx[1], j));
    float gv = tanh_f(ag + bias[2] + gxval(gx[2], j));
    float ov = sigm(ao + bias[3] + gxval(gx[3], j));
    cstate = fv * cstate + iv * gv;
    float h = ov * tanh_f(cstate);
    if (s == 0) ((f16*)&hbuf[(t + 1) & 1][0])[c] = (f16)h;
    hprev = h;
    __syncthreads();
  };

#pragma unroll 1
  for (int t0 = 0; t0 < TC; t0 += 16) {
    {
      int tn = t0 + 8;
#pragma unroll
      for (int g = 0; g < 4; ++g) gB[g] = *(const uint4*)(gxb + (size_t)g * TC + tn);
    }
#pragma unroll
    for (int j = 0; j < 8; ++j) STEP(gA, t0 + j, j);
    {
      int tm = t0 + 16; if (tm > TC - 8) tm = TC - 8;  // clamp (values unused)
#pragma unroll
      for (int g = 0; g < 4; ++g) gA[g] = *(const uint4*)(gxb + (size_t)g * TC + tm);
    }
#pragma unroll
    for (int j = 0; j < 8; ++j) STEP(gB, t0 + 8 + j, j);
  }

  if (h1x && s == 0) h1x[(size_t)(TC - 1) * HID] = (f16)hprev;
  if (s == 0) {
    P.hst[b * HID + c] = (float)(f16)hprev;  // chunk chain uses f16-rounded h
    P.cst[b * HID + c] = cstate;
    if (P.fin) P.fin[b * HID + c] = hprev;
  }
}

extern "C" void kernel_launch(void* const* d_in, const int* in_sizes, int n_in,
                              void* d_out, int out_size, void* d_ws,
                              size_t ws_size, hipStream_t stream) {
  const float* x    = (const float*)d_in[0];
  const float* h0   = (const float*)d_in[1];
  const float* c0   = (const float*)d_in[2];
  const float* Wih0 = (const float*)d_in[3];
  const float* Whh0 = (const float*)d_in[4];
  const float* bih0 = (const float*)d_in[5];
  const float* bhh0 = (const float*)d_in[6];
  const float* Wih1 = (const float*)d_in[7];
  const float* Whh1 = (const float*)d_in[8];
  const float* bih1 = (const float*)d_in[9];
  const float* bhh1 = (const float*)d_in[10];

  char* w = (char*)d_ws;
  f16* Gx0 = (f16*)w;      w += (size_t)B_ * TC * NG * 2;   // 33.5 MB
  f16* Gx1 = (f16*)w;      w += (size_t)B_ * TC * NG * 2;   // 33.5 MB
  f16* h1  = (f16*)w;      w += (size_t)B_ * TC * HID * 2;  // 8.4 MB
  float* sH0 = (float*)w;  w += (size_t)B_ * HID * 4;
  float* sC0 = (float*)w;  w += (size_t)B_ * HID * 4;
  float* sH1 = (float*)w;  w += (size_t)B_ * HID * 4;
  float* sC1 = (float*)w;

  const dim3 ggrid(B_ * TC / 128, 8);  // (256, 8)

  auto l0args = [&](int cc) {
    RecArgs a;
    a.Gx = Gx0; a.Whh = Whh0; a.bih = bih0; a.bhh = bhh0;
    a.hin = cc == 0 ? h0 : sH0; a.cin = cc == 0 ? c0 : sC0;
    a.hst = sH0; a.cst = sC0; a.h1out = h1; a.fin = nullptr;
    return a;
  };
  auto l1args = [&](int cc) {
    RecArgs a;
    a.Gx = Gx1; a.Whh = Whh1; a.bih = bih1; a.bhh = bhh1;
    a.hin = cc == 0 ? h0 + B_ * HID : sH1; a.cin = cc == 0 ? c0 + B_ * HID : sC1;
    a.hst = sH1; a.cst = sC1; a.h1out = nullptr;
    a.fin = cc == NC - 1 ? (float*)d_out : nullptr;
    return a;
  };

  RecArgs dummy = {};

  // chunk 0, layer 0
  gemm_xw<KX0, false><<<ggrid, 256, 0, stream>>>(
      x + (size_t)0 * TC * KX0, (size_t)T_ * KX0, Wih0, Gx0);
  lstm_rec2<<<B_, 512, 0, stream>>>(l0args(0), dummy, B_);

  for (int cc = 1; cc < NC; ++cc) {
    // x-side GEMMs for the upcoming pair: L1 uses h1(cc-1), L0 uses x(cc)
    gemm_xw<HID, true><<<ggrid, 256, 0, stream>>>(h1, 0, Wih1, Gx1);
    gemm_xw<KX0, false><<<ggrid, 256, 0, stream>>>(
        x + (size_t)cc * TC * KX0, (size_t)T_ * KX0, Wih0, Gx0);
    // L0 chunk cc  ||  L1 chunk cc-1  (512 blocks -> 2/CU)
    lstm_rec2<<<2 * B_, 512, 0, stream>>>(l0args(cc), l1args(cc - 1), B_);
  }

  // tail: layer 1, last chunk
  gemm_xw<HID, true><<<ggrid, 256, 0, stream>>>(h1, 0, Wih1, Gx1);
  lstm_rec2<<<B_, 512, 0, stream>>>(l1args(NC - 1), dummy, B_);
}

// Round 11
// 886.082 us; speedup vs baseline: 1.0267x; 1.0267x over previous
//
#include <hip/hip_runtime.h>

// OnsetLSTM: 2-layer LSTM, B=256, T=512, D=160, H=128, fp32 in/out.
//
// Architecture: x-side gate pre-acts (with bias folded in) via MFMA GEMM;
// recurrence keeps only W_hh in registers. Chunked layer pipeline NC=4:
// L0 chunk c runs concurrently with L1 chunk c-1.
//
// R11 key change: 256-thread rec blocks. hipcc's register budget is
// 65536 VGPRs per WORKGROUP (R4-R7: 512thr->128/thr, 1024thr->64/thr), so
// 256 threads unlock 256 VGPRs/thread: thread=(cell c, K-half s) holds all
// 4 gate rows x 32 pairs = 128 weight VGPRs spill-free. 4 waves/block =
// 1 wave/SIMD -> minimal barrier skew (R9/R10 ran 3500cy/step with 8-16
// waves resyncing every step; singles==pairs proved it wasn't VALU-bound).

typedef _Float16 f16;
typedef _Float16 f16x8 __attribute__((ext_vector_type(8)));
typedef float f32x4 __attribute__((ext_vector_type(4)));

#define B_  256
#define T_  512
#define HID 128
#define NG  512
#define KX0 160
#define NC  4
#define TC  128   // T_/NC

static __device__ __forceinline__ unsigned pack2(float a, float b) {
  union { f16 h[2]; unsigned u; } v;
  v.h[0] = (f16)a; v.h[1] = (f16)b;
  return v.u;
}

// v_dot2_f32_f16: d = a.h0*b.h0 + a.h1*b.h1 + c (CDNA4 VOP3P)
static __device__ __forceinline__ float dot2f(unsigned a, unsigned b, float c) {
  float d;
  asm("v_dot2_f32_f16 %0, %1, %2, %3" : "=v"(d) : "v"(a), "v"(b), "v"(c));
  return d;
}

static __device__ __forceinline__ float fast_rcp(float x) {
#if __has_builtin(__builtin_amdgcn_rcpf)
  return __builtin_amdgcn_rcpf(x);
#else
  return 1.0f / x;
#endif
}
static __device__ __forceinline__ float fast_exp2(float x) {
#if __has_builtin(__builtin_amdgcn_exp2f)
  return __builtin_amdgcn_exp2f(x);
#else
  return exp2f(x);
#endif
}
static __device__ __forceinline__ float sigm(float x) {
  return fast_rcp(1.0f + fast_exp2(x * -1.44269504f));
}
static __device__ __forceinline__ float tanh_f(float x) {
  float e = fast_exp2(x * 2.885390082f);
  return 1.0f - 2.0f * fast_rcp(e + 1.0f);
}

// one butterfly stage over lane^1 (s-halves)
static __device__ __forceinline__ float qp_add1(float v) {
  int iv = __builtin_bit_cast(int, v);
  int t = __builtin_amdgcn_update_dpp(iv, iv, 0xB1, 0xF, 0xF, true);
  return v + __builtin_bit_cast(float, t);
}

// extract f16 #j (compile-time after unroll) from an 8-half batch
static __device__ __forceinline__ float gxval(const uint4& g, int j) {
  unsigned w = (j >> 1) == 0 ? g.x : (j >> 1) == 1 ? g.y : (j >> 1) == 2 ? g.z : g.w;
  unsigned hs = (j & 1) ? (w >> 16) : (w & 0xffffu);
  f16 v = __builtin_bit_cast(f16, (unsigned short)hs);
  return (float)v;
}

// ======================= GEMM: Gx = A @ W^T (+bias), t-transposed store =====
// A: [B][Tc][K] (f32 strided x, or f16 contiguous h1). W: [512][K] f32.
// D layout: [(b*128 + cell)*4 + gate][t], t in [0,TC). bias[col] folded in.
template <int K, bool AF16>
__global__ __launch_bounds__(256) void gemm_xw(
    const void* __restrict__ Aptr, size_t bStride,
    const float* __restrict__ W,
    const float* __restrict__ bihp, const float* __restrict__ bhhp,
    f16* __restrict__ D) {
  constexpr int KP = K + 8;
  __shared__ f16 As[128][KP];
  __shared__ f16 Bs[64][KP];
  const int tid = threadIdx.x;
  const int mtile = blockIdx.x, ntile = blockIdx.y;

  if (AF16) {
    const f16* A = (const f16*)Aptr;
    for (int i = tid; i < 128 * (K / 8); i += 256) {
      int r = i / (K / 8), kk = (i % (K / 8)) * 8;
      size_t grow = (size_t)mtile * 128 + r;
      uint4 v = *(const uint4*)(A + grow * K + kk);
      *(uint4*)&As[r][kk] = v;
    }
  } else {
    const float* A = (const float*)Aptr;
    for (int i = tid; i < 128 * (K / 4); i += 256) {
      int r = i / (K / 4), kk = (i % (K / 4)) * 4;
      int grow = mtile * 128 + r;
      int bb = grow >> 7, tt = grow & (TC - 1);
      const float* p = A + (size_t)bb * bStride + (size_t)tt * K + kk;
      float4 v = *(const float4*)p;
      uint2 u;
      u.x = pack2(v.x, v.y);
      u.y = pack2(v.z, v.w);
      *(uint2*)&As[r][kk] = u;
    }
  }
  for (int i = tid; i < 64 * (K / 4); i += 256) {
    int r = i / (K / 4), kk = (i % (K / 4)) * 4;
    const float* p = W + (size_t)(ntile * 64 + r) * K + kk;
    float4 v = *(const float4*)p;
    uint2 u;
    u.x = pack2(v.x, v.y);
    u.y = pack2(v.z, v.w);
    *(uint2*)&Bs[r][kk] = u;
  }
  __syncthreads();

  const int w = tid >> 6, l = tid & 63;
  const int lr = l & 15, lg = l >> 4;
  f32x4 acc[2][4] = {};
#pragma unroll
  for (int ks = 0; ks < K / 32; ++ks) {
    f16x8 a0 = *(const f16x8*)&As[w * 32 + lr][ks * 32 + lg * 8];
    f16x8 a1 = *(const f16x8*)&As[w * 32 + 16 + lr][ks * 32 + lg * 8];
    f16x8 bf[4];
#pragma unroll
    for (int nj = 0; nj < 4; ++nj)
      bf[nj] = *(const f16x8*)&Bs[nj * 16 + lr][ks * 32 + lg * 8];
#pragma unroll
    for (int nj = 0; nj < 4; ++nj) {
      acc[0][nj] = __builtin_amdgcn_mfma_f32_16x16x32_f16(a0, bf[nj], acc[0][nj], 0, 0, 0);
      acc[1][nj] = __builtin_amdgcn_mfma_f32_16x16x32_f16(a1, bf[nj], acc[1][nj], 0, 0, 0);
    }
  }
  // C/D layout (m89): col = lane&15, row = (lane>>4)*4 + q. Rows are t.
#pragma unroll
  for (int mi = 0; mi < 2; ++mi) {
#pragma unroll
    for (int nj = 0; nj < 4; ++nj) {
      int col = ntile * 64 + nj * 16 + lr;
      float bsum = bihp[col] + bhhp[col];
      int cell = col & 127, gate = col >> 7;
      int rowbase = mtile * 128 + w * 32 + mi * 16 + lg * 4;
      int bb = rowbase >> 7, tt = rowbase & (TC - 1);
      unsigned lo = pack2(acc[mi][nj][0] + bsum, acc[mi][nj][1] + bsum);
      unsigned hi = pack2(acc[mi][nj][2] + bsum, acc[mi][nj][3] + bsum);
      size_t idx = (((size_t)bb * HID + cell) * 4 + gate) * TC + tt;
      uint2 u; u.x = lo; u.y = hi;
      *(uint2*)(D + idx) = u;
    }
  }
}

// ======================= Recurrence (chunk, possibly 2 layers) ==============
struct RecArgs {
  const f16* Gx;      // [(b*128+cell)*4+gate][TC], bias included
  const float* Whh;   // [512][128]
  const float* hin; const float* cin;   // [B][128] f32
  float* hst; float* cst;               // [B][128] f32
  f16* h1out;                            // [B][TC][128] or null
  float* fin;                            // [B][128] or null
};

__global__ __launch_bounds__(256) void lstm_rec2(RecArgs A, RecArgs B, int nA) {
  const RecArgs& P = ((int)blockIdx.x < nA) ? A : B;
  const int b = ((int)blockIdx.x < nA) ? blockIdx.x : blockIdx.x - nA;
  const int tid = threadIdx.x;
  const int c = tid >> 1, s = tid & 1;  // cell, K-half
  __shared__ unsigned hbuf[2][64];

  // W_hh rows for all 4 gates of cell c, pairs [32s, 32s+32) -> 128 VGPRs
  unsigned wh[4][32];
#pragma unroll
  for (int g = 0; g < 4; ++g) {
    const int r = g * HID + c;
#pragma unroll
    for (int j = 0; j < 32; ++j) {
      int p = 32 * s + j;
      wh[g][j] = pack2(P.Whh[(size_t)r * HID + 2 * p], P.Whh[(size_t)r * HID + 2 * p + 1]);
    }
  }
  float cstate = P.cin[b * HID + c];
  if (tid < 64)
    hbuf[0][tid] = pack2(P.hin[b * HID + 2 * tid], P.hin[b * HID + 2 * tid + 1]);

  const f16* gxb = P.Gx + ((size_t)b * HID + c) * 4 * TC;
  f16* h1x = P.h1out ? P.h1out + (size_t)b * TC * HID + c : (f16*)nullptr;
  __syncthreads();

  float hprev = 0.f;

#pragma unroll 1
  for (int t0 = 0; t0 < TC; t0 += 8) {
    uint4 g4[4];
#pragma unroll
    for (int g = 0; g < 4; ++g) g4[g] = *(const uint4*)(gxb + (size_t)g * TC + t0);

#pragma unroll
    for (int j = 0; j < 8; ++j) {
      const int t = t0 + j;
      // early store of previous step's h1 (ack retires across this step)
      if (h1x && s == 0 && (j > 0 || t0 > 0)) h1x[(size_t)(t - 1) * HID] = (f16)hprev;
      const uint4* hs4 = (const uint4*)&hbuf[t & 1][32 * s];
      float ai = 0.f, af = 0.f, ag = 0.f, ao = 0.f;
#pragma unroll
      for (int k = 0; k < 8; ++k) {
        uint4 v = hs4[k];
        ai = dot2f(v.x, wh[0][4 * k + 0], ai); ai = dot2f(v.y, wh[0][4 * k + 1], ai);
        ai = dot2f(v.z, wh[0][4 * k + 2], ai); ai = dot2f(v.w, wh[0][4 * k + 3], ai);
        af = dot2f(v.x, wh[1][4 * k + 0], af); af = dot2f(v.y, wh[1][4 * k + 1], af);
        af = dot2f(v.z, wh[1][4 * k + 2], af); af = dot2f(v.w, wh[1][4 * k + 3], af);
        ag = dot2f(v.x, wh[2][4 * k + 0], ag); ag = dot2f(v.y, wh[2][4 * k + 1], ag);
        ag = dot2f(v.z, wh[2][4 * k + 2], ag); ag = dot2f(v.w, wh[2][4 * k + 3], ag);
        ao = dot2f(v.x, wh[3][4 * k + 0], ao); ao = dot2f(v.y, wh[3][4 * k + 1], ao);
        ao = dot2f(v.z, wh[3][4 * k + 2], ao); ao = dot2f(v.w, wh[3][4 * k + 3], ao);
      }
      // single butterfly stage (lane^1): both s-halves get full K-sums
      ai = qp_add1(ai); af = qp_add1(af); ag = qp_add1(ag); ao = qp_add1(ao);

      float iv = sigm(ai + gxval(g4[0], j));
      float fv = sigm(af + gxval(g4[1], j));
      float gv = tanh_f(ag + gxval(g4[2], j));
      float ov = sigm(ao + gxval(g4[3], j));
      cstate = fv * cstate + iv * gv;
      float h = ov * tanh_f(cstate);
      if (s == 0) ((f16*)&hbuf[(t + 1) & 1][0])[c] = (f16)h;
      hprev = h;
      __syncthreads();
    }
  }

  if (h1x && s == 0) h1x[(size_t)(TC - 1) * HID] = (f16)hprev;
  if (s == 0) {
    P.hst[b * HID + c] = (float)(f16)hprev;  // chunk chain uses f16-rounded h
    P.cst[b * HID + c] = cstate;
    if (P.fin) P.fin[b * HID + c] = hprev;
  }
}

extern "C" void kernel_launch(void* const* d_in, const int* in_sizes, int n_in,
                              void* d_out, int out_size, void* d_ws,
                              size_t ws_size, hipStream_t stream) {
  const float* x    = (const float*)d_in[0];
  const float* h0   = (const float*)d_in[1];
  const float* c0   = (const float*)d_in[2];
  const float* Wih0 = (const float*)d_in[3];
  const float* Whh0 = (const float*)d_in[4];
  const float* bih0 = (const float*)d_in[5];
  const float* bhh0 = (const float*)d_in[6];
  const float* Wih1 = (const float*)d_in[7];
  const float* Whh1 = (const float*)d_in[8];
  const float* bih1 = (const float*)d_in[9];
  const float* bhh1 = (const float*)d_in[10];

  char* w = (char*)d_ws;
  f16* Gx0 = (f16*)w;      w += (size_t)B_ * TC * NG * 2;   // 33.5 MB
  f16* Gx1 = (f16*)w;      w += (size_t)B_ * TC * NG * 2;   // 33.5 MB
  f16* h1  = (f16*)w;      w += (size_t)B_ * TC * HID * 2;  // 8.4 MB
  float* sH0 = (float*)w;  w += (size_t)B_ * HID * 4;
  float* sC0 = (float*)w;  w += (size_t)B_ * HID * 4;
  float* sH1 = (float*)w;  w += (size_t)B_ * HID * 4;
  float* sC1 = (float*)w;

  const dim3 ggrid(B_ * TC / 128, 8);  // (256, 8)

  auto l0args = [&](int cc) {
    RecArgs a;
    a.Gx = Gx0; a.Whh = Whh0;
    a.hin = cc == 0 ? h0 : sH0; a.cin = cc == 0 ? c0 : sC0;
    a.hst = sH0; a.cst = sC0; a.h1out = h1; a.fin = nullptr;
    return a;
  };
  auto l1args = [&](int cc) {
    RecArgs a;
    a.Gx = Gx1; a.Whh = Whh1;
    a.hin = cc == 0 ? h0 + B_ * HID : sH1; a.cin = cc == 0 ? c0 + B_ * HID : sC1;
    a.hst = sH1; a.cst = sC1; a.h1out = nullptr;
    a.fin = cc == NC - 1 ? (float*)d_out : nullptr;
    return a;
  };

  RecArgs dummy = {};

  // chunk 0, layer 0
  gemm_xw<KX0, false><<<ggrid, 256, 0, stream>>>(
      x + (size_t)0 * TC * KX0, (size_t)T_ * KX0, Wih0, bih0, bhh0, Gx0);
  lstm_rec2<<<B_, 256, 0, stream>>>(l0args(0), dummy, B_);

  for (int cc = 1; cc < NC; ++cc) {
    // x-side GEMMs for the upcoming pair: L1 uses h1(cc-1), L0 uses x(cc)
    gemm_xw<HID, true><<<ggrid, 256, 0, stream>>>(h1, 0, Wih1, bih1, bhh1, Gx1);
    gemm_xw<KX0, false><<<ggrid, 256, 0, stream>>>(
        x + (size_t)cc * TC * KX0, (size_t)T_ * KX0, Wih0, bih0, bhh0, Gx0);
    // L0 chunk cc  ||  L1 chunk cc-1  (512 blocks -> 2/CU)
    lstm_rec2<<<2 * B_, 256, 0, stream>>>(l0args(cc), l1args(cc - 1), B_);
  }

  // tail: layer 1, last chunk
  gemm_xw<HID, true><<<ggrid, 256, 0, stream>>>(h1, 0, Wih1, bih1, bhh1, Gx1);
  lstm_rec2<<<B_, 256, 0, stream>>>(l1args(NC - 1), dummy, B_);
}